// Round 3
// baseline (2000.280 us; speedup 1.0000x reference)
//
#include <hip/hip_runtime.h>
#include <math.h>

#define N_NODES 100000
#define NB 1563              // ceil(N_NODES / 64) buckets of 64 dst nodes
#define BN_EPS 1e-5f
#define PART_BLOCKS 128

// ---------------------------------------------------------------------------
__global__ void zero_misc_k(float* stats, int* gcnt) {
    int gid = blockIdx.x * blockDim.x + threadIdx.x;
    if (gid < 384) stats[gid] = 0.f;
    if (gid < NB) gcnt[gid] = 0;
}

// per-bucket edge histogram (bucket = dst >> 6), block-aggregated in LDS
__global__ __launch_bounds__(256) void histA_k(const int* __restrict__ ei,
                                               int* __restrict__ gcnt, int E) {
    __shared__ int cnt[NB];
    for (int i = threadIdx.x; i < NB; i += 256) cnt[i] = 0;
    __syncthreads();
    int per = (E + gridDim.x - 1) / gridDim.x;
    int s0 = blockIdx.x * per, s1 = min(E, s0 + per);
    for (int e = s0 + threadIdx.x; e < s1; e += 256)
        atomicAdd(&cnt[ei[E + e] >> 6], 1);
    __syncthreads();
    for (int i = threadIdx.x; i < NB; i += 256)
        if (cnt[i]) atomicAdd(&gcnt[i], cnt[i]);
}

// exclusive scan of NB bucket counts (single block, 7 elems/thread)
__global__ __launch_bounds__(256) void scanA_k(const int* __restrict__ gcnt,
                                               int* __restrict__ bbase,
                                               int* __restrict__ gcursor) {
    __shared__ int tmp[256];
    int t = threadIdx.x;
    int v[7];
    int s = 0;
#pragma unroll
    for (int j = 0; j < 7; ++j) {
        int idx = t * 7 + j;
        v[j] = (idx < NB) ? gcnt[idx] : 0;
        s += v[j];
    }
    tmp[t] = s;
    __syncthreads();
    for (int off = 1; off < 256; off <<= 1) {
        int a = (t >= off) ? tmp[t - off] : 0;
        __syncthreads();
        tmp[t] += a;
        __syncthreads();
    }
    int run = tmp[t] - s;
#pragma unroll
    for (int j = 0; j < 7; ++j) {
        int idx = t * 7 + j;
        if (idx < NB) { bbase[idx] = run; gcursor[idx] = run; }
        run += v[j];
    }
    if (t == 255) bbase[NB] = run;  // == E
}

// bucket-partition edges: part[] entries are (dst&63)<<20 | src, bucket-contiguous
__global__ __launch_bounds__(256) void partA_k(const int* __restrict__ ei,
                                               int* __restrict__ gcursor,
                                               int* __restrict__ part, int E) {
    __shared__ int cnt[NB];
    __shared__ int base[NB];
    for (int i = threadIdx.x; i < NB; i += 256) cnt[i] = 0;
    __syncthreads();
    int per = (E + gridDim.x - 1) / gridDim.x;
    int s0 = blockIdx.x * per, s1 = min(E, s0 + per);
    for (int e = s0 + threadIdx.x; e < s1; e += 256)
        atomicAdd(&cnt[ei[E + e] >> 6], 1);
    __syncthreads();
    for (int i = threadIdx.x; i < NB; i += 256) {
        int c = cnt[i];
        base[i] = c ? atomicAdd(&gcursor[i], c) : 0;
    }
    __syncthreads();
    for (int i = threadIdx.x; i < NB; i += 256) cnt[i] = 0;
    __syncthreads();
    for (int e = s0 + threadIdx.x; e < s1; e += 256) {
        int s = ei[e], d = ei[E + e];
        int b = d >> 6, dl = d & 63;
        int lo = atomicAdd(&cnt[b], 1);
        part[base[b] + lo] = (dl << 20) | s;
    }
}

// ---------------------------------------------------------------------------
// Fused GIN layer: block = one 64-node bucket.
//   load prev-h rows (apply prev BN+relu unless FIRST), self-term + LDS-atomic
//   neighbor gather into xs, then h = relu(relu(xs@W1+b1)@W2+b2), BN stats,
//   store h to hout.
template <bool FIRST>
__global__ __launch_bounds__(256) void layer_k(
    const float* __restrict__ hin, const float* __restrict__ pstats,
    const float* __restrict__ pg, const float* __restrict__ pbt,
    const int* __restrict__ bbase, const int* __restrict__ part,
    const float* __restrict__ epsp,
    const float* __restrict__ w1, const float* __restrict__ b1,
    const float* __restrict__ w2, const float* __restrict__ b2,
    float* __restrict__ hout, float* __restrict__ stats) {
    __shared__ float xs[64][68];   // xs[channel][row]
    __shared__ float wsh[4096];
    __shared__ float bsh[64];
    __shared__ float ssc[64], sof[64];
    __shared__ float sred[128];

    int tid = threadIdx.x;
    int bkt = blockIdx.x;
    int r0 = bkt * 64;

    if (tid < 64) {
        if (FIRST) {
            ssc[tid] = 1.f;
            sof[tid] = 0.f;
        } else {
            float mean = pstats[tid] * (1.f / N_NODES);
            float var = pstats[64 + tid] * (1.f / N_NODES) - mean * mean;
            float sc = pg[tid] * rsqrtf(var + BN_EPS);
            ssc[tid] = sc;
            sof[tid] = pbt[tid] - mean * sc;
        }
    }
    if (tid < 128) sred[tid] = 0.f;
    const float4* w14 = reinterpret_cast<const float4*>(w1);
    float4* wsh4 = reinterpret_cast<float4*>(wsh);
#pragma unroll
    for (int i = 0; i < 4; ++i) wsh4[tid + i * 256] = w14[tid + i * 256];
    if (tid < 64) bsh[tid] = b1[tid];
    __syncthreads();  // ssc/sof ready

    float eps1 = 1.0f + *epsp;

    // self term: (1+eps) * bnrelu(hin[node]); zero pad rows
    {
        int rr = tid >> 4, cg = tid & 15;
#pragma unroll
        for (int i = 0; i < 4; ++i) {
            int r = rr + i * 16;
            int node = r0 + r;
            float4 v = make_float4(0.f, 0.f, 0.f, 0.f);
            if (node < N_NODES) {
                v = reinterpret_cast<const float4*>(hin + (size_t)node * 64)[cg];
                int c = cg * 4;
                if (!FIRST) {
                    v.x = fmaxf(fmaf(v.x, ssc[c + 0], sof[c + 0]), 0.f);
                    v.y = fmaxf(fmaf(v.y, ssc[c + 1], sof[c + 1]), 0.f);
                    v.z = fmaxf(fmaf(v.z, ssc[c + 2], sof[c + 2]), 0.f);
                    v.w = fmaxf(fmaf(v.w, ssc[c + 3], sof[c + 3]), 0.f);
                }
                v.x *= eps1; v.y *= eps1; v.z *= eps1; v.w *= eps1;
            }
            xs[cg * 4 + 0][r] = v.x;
            xs[cg * 4 + 1][r] = v.y;
            xs[cg * 4 + 2][r] = v.z;
            xs[cg * 4 + 3][r] = v.w;
        }
    }
    __syncthreads();

    // neighbor gather: one edge per thread, 64 LDS float atomics each
    {
        int e0 = bbase[bkt], e1 = bbase[bkt + 1];
        for (int i = e0 + tid; i < e1; i += 256) {
            int u = part[i];
            int s = u & 0xFFFFF;
            int dl = u >> 20;
            const float4* row = reinterpret_cast<const float4*>(hin + (size_t)s * 64);
#pragma unroll
            for (int q = 0; q < 16; ++q) {
                float4 v = row[q];
                int c = q * 4;
                if (!FIRST) {
                    v.x = fmaxf(fmaf(v.x, ssc[c + 0], sof[c + 0]), 0.f);
                    v.y = fmaxf(fmaf(v.y, ssc[c + 1], sof[c + 1]), 0.f);
                    v.z = fmaxf(fmaf(v.z, ssc[c + 2], sof[c + 2]), 0.f);
                    v.w = fmaxf(fmaf(v.w, ssc[c + 3], sof[c + 3]), 0.f);
                }
                atomicAdd(&xs[c + 0][dl], v.x);
                atomicAdd(&xs[c + 1][dl], v.y);
                atomicAdd(&xs[c + 2][dl], v.z);
                atomicAdd(&xs[c + 3][dl], v.w);
            }
        }
    }
    __syncthreads();

    int tr = tid & 15, tc = tid >> 4;
    int r = tr * 4, c = tc * 4;
    float acc[4][4];

    // ---- GEMM1: relu(xs @ W1 + b1) ----
#pragma unroll
    for (int i = 0; i < 4; ++i)
#pragma unroll
        for (int j = 0; j < 4; ++j) acc[i][j] = 0.f;
#pragma unroll 8
    for (int k = 0; k < 64; ++k) {
        float4 xv = *reinterpret_cast<const float4*>(&xs[k][r]);
        float4 wv = *reinterpret_cast<const float4*>(&wsh[k * 64 + c]);
        float xa[4] = {xv.x, xv.y, xv.z, xv.w};
        float wa[4] = {wv.x, wv.y, wv.z, wv.w};
#pragma unroll
        for (int i = 0; i < 4; ++i)
#pragma unroll
            for (int j = 0; j < 4; ++j) acc[i][j] = fmaf(xa[i], wa[j], acc[i][j]);
    }
#pragma unroll
    for (int j = 0; j < 4; ++j) {
        float bj = bsh[c + j];
#pragma unroll
        for (int i = 0; i < 4; ++i) acc[i][j] = fmaxf(acc[i][j] + bj, 0.f);
    }
    __syncthreads();  // all reads of xs/wsh done

    // write h1 transposed into xs; hot-swap W2/b2
#pragma unroll
    for (int i = 0; i < 4; ++i)
#pragma unroll
        for (int j = 0; j < 4; ++j) xs[c + j][r + i] = acc[i][j];
    const float4* w24 = reinterpret_cast<const float4*>(w2);
#pragma unroll
    for (int i = 0; i < 4; ++i) wsh4[tid + i * 256] = w24[tid + i * 256];
    if (tid < 64) bsh[tid] = b2[tid];
    __syncthreads();

    // ---- GEMM2: relu(h1 @ W2 + b2) ----
#pragma unroll
    for (int i = 0; i < 4; ++i)
#pragma unroll
        for (int j = 0; j < 4; ++j) acc[i][j] = 0.f;
#pragma unroll 8
    for (int k = 0; k < 64; ++k) {
        float4 xv = *reinterpret_cast<const float4*>(&xs[k][r]);
        float4 wv = *reinterpret_cast<const float4*>(&wsh[k * 64 + c]);
        float xa[4] = {xv.x, xv.y, xv.z, xv.w};
        float wa[4] = {wv.x, wv.y, wv.z, wv.w};
#pragma unroll
        for (int i = 0; i < 4; ++i)
#pragma unroll
            for (int j = 0; j < 4; ++j) acc[i][j] = fmaf(xa[i], wa[j], acc[i][j]);
    }
#pragma unroll
    for (int j = 0; j < 4; ++j) {
        float bj = bsh[c + j];
#pragma unroll
        for (int i = 0; i < 4; ++i) acc[i][j] = fmaxf(acc[i][j] + bj, 0.f);
    }

    // store h + BN stats
#pragma unroll
    for (int i = 0; i < 4; ++i) {
        int row = r0 + r + i;
        if (row < N_NODES) {
            float4 o = make_float4(acc[i][0], acc[i][1], acc[i][2], acc[i][3]);
            *reinterpret_cast<float4*>(hout + (size_t)row * 64 + c) = o;
        }
    }
#pragma unroll
    for (int j = 0; j < 4; ++j) {
        float s = 0.f, q = 0.f;
#pragma unroll
        for (int i = 0; i < 4; ++i) {
            if (r0 + r + i < N_NODES) {
                s += acc[i][j];
                q += acc[i][j] * acc[i][j];
            }
        }
        atomicAdd(&sred[c + j], s);
        atomicAdd(&sred[64 + c + j], q);
    }
    __syncthreads();
    if (tid < 128) atomicAdd(&stats[tid], sred[tid]);
}

// ---------------------------------------------------------------------------
// out[N x 16] = bnrelu3(h) @ wl + bl
__global__ __launch_bounds__(256) void final_k(const float* __restrict__ hin,
                                               const float* __restrict__ pstats,
                                               const float* __restrict__ pg,
                                               const float* __restrict__ pbt,
                                               const float* __restrict__ wl,
                                               const float* __restrict__ bl,
                                               float* __restrict__ out) {
    __shared__ float xs[64][68];
    __shared__ float wsh[64 * 16];
    __shared__ float bsh[16];
    __shared__ float ssc[64], sof[64];
    int tid = threadIdx.x;
    int r0 = blockIdx.x * 64;

    if (tid < 64) {
        float mean = pstats[tid] * (1.f / N_NODES);
        float var = pstats[64 + tid] * (1.f / N_NODES) - mean * mean;
        float sc = pg[tid] * rsqrtf(var + BN_EPS);
        ssc[tid] = sc;
        sof[tid] = pbt[tid] - mean * sc;
    }
    reinterpret_cast<float4*>(wsh)[tid] = reinterpret_cast<const float4*>(wl)[tid];
    if (tid < 16) bsh[tid] = bl[tid];
    __syncthreads();

    {
        int rr = tid >> 4, cg = tid & 15;
#pragma unroll
        for (int i = 0; i < 4; ++i) {
            int r = rr + i * 16;
            float4 v = make_float4(0.f, 0.f, 0.f, 0.f);
            if (r0 + r < N_NODES) {
                v = reinterpret_cast<const float4*>(hin + (size_t)(r0 + r) * 64)[cg];
                int c = cg * 4;
                v.x = fmaxf(fmaf(v.x, ssc[c + 0], sof[c + 0]), 0.f);
                v.y = fmaxf(fmaf(v.y, ssc[c + 1], sof[c + 1]), 0.f);
                v.z = fmaxf(fmaf(v.z, ssc[c + 2], sof[c + 2]), 0.f);
                v.w = fmaxf(fmaf(v.w, ssc[c + 3], sof[c + 3]), 0.f);
            }
            xs[cg * 4 + 0][r] = v.x;
            xs[cg * 4 + 1][r] = v.y;
            xs[cg * 4 + 2][r] = v.z;
            xs[cg * 4 + 3][r] = v.w;
        }
    }
    __syncthreads();

    int tc = tid & 3, r = tid >> 2;
    int c = tc * 4;
    float acc0 = 0.f, acc1 = 0.f, acc2 = 0.f, acc3 = 0.f;
#pragma unroll 8
    for (int k = 0; k < 64; ++k) {
        float xv = xs[k][r];
        float4 wv = *reinterpret_cast<const float4*>(&wsh[k * 16 + c]);
        acc0 = fmaf(xv, wv.x, acc0);
        acc1 = fmaf(xv, wv.y, acc1);
        acc2 = fmaf(xv, wv.z, acc2);
        acc3 = fmaf(xv, wv.w, acc3);
    }
    int row = r0 + r;
    if (row < N_NODES) {
        float4 o = make_float4(acc0 + bsh[c], acc1 + bsh[c + 1], acc2 + bsh[c + 2], acc3 + bsh[c + 3]);
        *reinterpret_cast<float4*>(out + (size_t)row * 16 + c) = o;
    }
}

// ---------------------------------------------------------------------------
extern "C" void kernel_launch(void* const* d_in, const int* in_sizes, int n_in,
                              void* d_out, int out_size, void* d_ws, size_t ws_size,
                              hipStream_t stream) {
    const float* x = (const float*)d_in[0];
    const int* ei = (const int*)d_in[1];
    const int E = in_sizes[1] / 2;

    const float* eps[3] = {(const float*)d_in[2], (const float*)d_in[9], (const float*)d_in[16]};
    const float* w1[3]  = {(const float*)d_in[3], (const float*)d_in[10], (const float*)d_in[17]};
    const float* b1[3]  = {(const float*)d_in[4], (const float*)d_in[11], (const float*)d_in[18]};
    const float* w2[3]  = {(const float*)d_in[5], (const float*)d_in[12], (const float*)d_in[19]};
    const float* b2[3]  = {(const float*)d_in[6], (const float*)d_in[13], (const float*)d_in[20]};
    const float* g[3]   = {(const float*)d_in[7], (const float*)d_in[14], (const float*)d_in[21]};
    const float* bt[3]  = {(const float*)d_in[8], (const float*)d_in[15], (const float*)d_in[22]};
    const float* wl = (const float*)d_in[23];
    const float* bl = (const float*)d_in[24];

    // workspace layout
    float* ha    = (float*)d_ws;
    float* hb    = ha + (size_t)N_NODES * 64;
    float* stats = hb + (size_t)N_NODES * 64;
    int* gcnt    = (int*)(stats + 384);
    int* bbase   = gcnt + NB;
    int* gcursor = bbase + (NB + 1);
    int* part_ws = gcursor + NB;
    size_t used = (size_t)((char*)part_ws - (char*)d_ws);
    // part: E ints; d_out (N*16 f32 = E*4 bytes) is a valid fallback scratch
    int* part = (used + (size_t)E * 4 <= ws_size) ? part_ws : (int*)d_out;

    // ---- bucket partition build (once) ----
    zero_misc_k<<<(NB + 255) / 256, 256, 0, stream>>>(stats, gcnt);
    histA_k<<<PART_BLOCKS, 256, 0, stream>>>(ei, gcnt, E);
    scanA_k<<<1, 256, 0, stream>>>(gcnt, bbase, gcursor);
    partA_k<<<PART_BLOCKS, 256, 0, stream>>>(ei, gcursor, part, E);

    // ---- 3 fused GIN layers ----
    layer_k<true><<<NB, 256, 0, stream>>>(x, nullptr, nullptr, nullptr, bbase, part,
                                          eps[0], w1[0], b1[0], w2[0], b2[0], ha, stats + 0);
    layer_k<false><<<NB, 256, 0, stream>>>(ha, stats + 0, g[0], bt[0], bbase, part,
                                           eps[1], w1[1], b1[1], w2[1], b2[1], hb, stats + 128);
    layer_k<false><<<NB, 256, 0, stream>>>(hb, stats + 128, g[1], bt[1], bbase, part,
                                           eps[2], w1[2], b1[2], w2[2], b2[2], ha, stats + 256);

    // ---- final linear with BN3 fused ----
    final_k<<<NB, 256, 0, stream>>>(ha, stats + 256, g[2], bt[2], wl, bl, (float*)d_out);
}

// Round 4
// 552.778 us; speedup vs baseline: 3.6186x; 3.6186x over previous
//
#include <hip/hip_runtime.h>
#include <math.h>

#define N_NODES 100000
#define NB 1563              // ceil(N_NODES / 64) buckets of 64 dst nodes
#define BN_EPS 1e-5f
#define PART_BLOCKS 128

// ---------------------------------------------------------------------------
__global__ void zero_misc_k(float* stats, int* gcnt) {
    int gid = blockIdx.x * blockDim.x + threadIdx.x;
    if (gid < 384) stats[gid] = 0.f;
    if (gid < NB) gcnt[gid] = 0;
}

// per-bucket edge histogram (bucket = dst >> 6), block-aggregated in LDS
__global__ __launch_bounds__(256) void histA_k(const int* __restrict__ ei,
                                               int* __restrict__ gcnt, int E) {
    __shared__ int cnt[NB];
    for (int i = threadIdx.x; i < NB; i += 256) cnt[i] = 0;
    __syncthreads();
    int per = (E + gridDim.x - 1) / gridDim.x;
    int s0 = blockIdx.x * per, s1 = min(E, s0 + per);
    for (int e = s0 + threadIdx.x; e < s1; e += 256)
        atomicAdd(&cnt[ei[E + e] >> 6], 1);
    __syncthreads();
    for (int i = threadIdx.x; i < NB; i += 256)
        if (cnt[i]) atomicAdd(&gcnt[i], cnt[i]);
}

// exclusive scan of NB bucket counts (single block, 7 elems/thread)
__global__ __launch_bounds__(256) void scanA_k(const int* __restrict__ gcnt,
                                               int* __restrict__ bbase,
                                               int* __restrict__ gcursor) {
    __shared__ int tmp[256];
    int t = threadIdx.x;
    int v[7];
    int s = 0;
#pragma unroll
    for (int j = 0; j < 7; ++j) {
        int idx = t * 7 + j;
        v[j] = (idx < NB) ? gcnt[idx] : 0;
        s += v[j];
    }
    tmp[t] = s;
    __syncthreads();
    for (int off = 1; off < 256; off <<= 1) {
        int a = (t >= off) ? tmp[t - off] : 0;
        __syncthreads();
        tmp[t] += a;
        __syncthreads();
    }
    int run = tmp[t] - s;
#pragma unroll
    for (int j = 0; j < 7; ++j) {
        int idx = t * 7 + j;
        if (idx < NB) { bbase[idx] = run; gcursor[idx] = run; }
        run += v[j];
    }
    if (t == 255) bbase[NB] = run;  // == E
}

// bucket-partition edges: part[] entries are (dst&63)<<20 | src, bucket-contiguous
__global__ __launch_bounds__(256) void partA_k(const int* __restrict__ ei,
                                               int* __restrict__ gcursor,
                                               int* __restrict__ part, int E) {
    __shared__ int cnt[NB];
    __shared__ int base[NB];
    for (int i = threadIdx.x; i < NB; i += 256) cnt[i] = 0;
    __syncthreads();
    int per = (E + gridDim.x - 1) / gridDim.x;
    int s0 = blockIdx.x * per, s1 = min(E, s0 + per);
    for (int e = s0 + threadIdx.x; e < s1; e += 256)
        atomicAdd(&cnt[ei[E + e] >> 6], 1);
    __syncthreads();
    for (int i = threadIdx.x; i < NB; i += 256) {
        int c = cnt[i];
        base[i] = c ? atomicAdd(&gcursor[i], c) : 0;
    }
    __syncthreads();
    for (int i = threadIdx.x; i < NB; i += 256) cnt[i] = 0;
    __syncthreads();
    for (int e = s0 + threadIdx.x; e < s1; e += 256) {
        int s = ei[e], d = ei[E + e];
        int b = d >> 6, dl = d & 63;
        int lo = atomicAdd(&cnt[b], 1);
        part[base[b] + lo] = (dl << 20) | s;
    }
}

// per-bucket LDS counting sort: part (bucket-contiguous) -> csr_src (node-ordered)
// + row_ptr. One block per bucket; writes confined to the bucket's csr range.
__global__ __launch_bounds__(256) void sortB_k(const int* __restrict__ part,
                                               const int* __restrict__ bbase,
                                               int* __restrict__ row_ptr,
                                               int* __restrict__ csr_src) {
    __shared__ int cnt[64];
    __shared__ int cur[64];
    int b = blockIdx.x;
    int t = threadIdx.x;
    int e0 = bbase[b], e1 = bbase[b + 1];
    if (t < 64) cnt[t] = 0;
    __syncthreads();
    for (int i = e0 + t; i < e1; i += 256) atomicAdd(&cnt[(part[i] >> 20) & 63], 1);
    __syncthreads();
    if (t < 64) {
        int c = cnt[t];
        int v = c;
        // inclusive wave scan over 64 lanes
        for (int off = 1; off < 64; off <<= 1) {
            int u = __shfl_up(v, off, 64);
            if (t >= off) v += u;
        }
        int excl = v - c;
        int node = b * 64 + t;
        if (node <= N_NODES) row_ptr[node] = e0 + excl;
        cur[t] = e0 + excl;
    }
    __syncthreads();
    for (int i = e0 + t; i < e1; i += 256) {
        int u = part[i];
        int dl = (u >> 20) & 63;
        int pos = atomicAdd(&cur[dl], 1);
        csr_src[pos] = u & 0xFFFFF;
    }
}

// ---------------------------------------------------------------------------
// Fused GIN layer: block = 64 dst nodes.
//   Phase A: register gather over CSR (apply prev BN+relu on load unless FIRST),
//            (1+eps)*self + neighbor sum -> xs transposed.
//   Phase B: h1 = relu(xs@W1+b1); transpose into xs; hot-swap W2.
//   Phase C: h  = relu(h1@W2+b2); store + BN stats.
template <bool FIRST>
__global__ __launch_bounds__(256) void layer_k(
    const float* __restrict__ hin, const float* __restrict__ pstats,
    const float* __restrict__ pg, const float* __restrict__ pbt,
    const int* __restrict__ row_ptr, const int* __restrict__ csr_src,
    const float* __restrict__ epsp,
    const float* __restrict__ w1, const float* __restrict__ b1,
    const float* __restrict__ w2, const float* __restrict__ b2,
    float* __restrict__ hout, float* __restrict__ stats) {
    __shared__ float xs[64][68];   // xs[channel][row]
    __shared__ float wsh[4096];
    __shared__ float bsh[64];
    __shared__ float ssc[64], sof[64];
    __shared__ float sred[128];

    int tid = threadIdx.x;
    int r0 = blockIdx.x * 64;

    if (tid < 64) {
        if (FIRST) {
            ssc[tid] = 1.f;
            sof[tid] = 0.f;
        } else {
            float mean = pstats[tid] * (1.f / N_NODES);
            float var = pstats[64 + tid] * (1.f / N_NODES) - mean * mean;
            float sc = pg[tid] * rsqrtf(var + BN_EPS);
            ssc[tid] = sc;
            sof[tid] = pbt[tid] - mean * sc;
        }
    }
    if (tid < 128) sred[tid] = 0.f;
    const float4* w14 = reinterpret_cast<const float4*>(w1);
    float4* wsh4 = reinterpret_cast<float4*>(wsh);
#pragma unroll
    for (int i = 0; i < 4; ++i) wsh4[tid + i * 256] = w14[tid + i * 256];
    if (tid < 64) bsh[tid] = b1[tid];
    __syncthreads();  // ssc/sof ready for gather

    float eps1 = 1.0f + *epsp;
    float s0 = ssc[(tid & 15) * 4 + 0], s1 = ssc[(tid & 15) * 4 + 1];
    float s2 = ssc[(tid & 15) * 4 + 2], s3 = ssc[(tid & 15) * 4 + 3];
    float o0 = sof[(tid & 15) * 4 + 0], o1 = sof[(tid & 15) * 4 + 1];
    float o2 = sof[(tid & 15) * 4 + 2], o3 = sof[(tid & 15) * 4 + 3];

    // Phase A: register gather, 16 lanes per node, 4 nodes per lane-group
    {
        int rr = tid >> 4, cg = tid & 15;
#pragma unroll
        for (int i = 0; i < 4; ++i) {
            int r = rr + i * 16;
            int node = r0 + r;
            float4 acc = make_float4(0.f, 0.f, 0.f, 0.f);
            if (node < N_NODES) {
                float4 v = reinterpret_cast<const float4*>(hin + (size_t)node * 64)[cg];
                if (!FIRST) {
                    v.x = fmaxf(fmaf(v.x, s0, o0), 0.f);
                    v.y = fmaxf(fmaf(v.y, s1, o1), 0.f);
                    v.z = fmaxf(fmaf(v.z, s2, o2), 0.f);
                    v.w = fmaxf(fmaf(v.w, s3, o3), 0.f);
                }
                acc.x = v.x * eps1; acc.y = v.y * eps1;
                acc.z = v.z * eps1; acc.w = v.w * eps1;
                int j0 = row_ptr[node], j1 = row_ptr[node + 1];
                for (int j = j0; j < j1; ++j) {
                    int sidx = csr_src[j];
                    float4 u = reinterpret_cast<const float4*>(hin + (size_t)sidx * 64)[cg];
                    if (!FIRST) {
                        u.x = fmaxf(fmaf(u.x, s0, o0), 0.f);
                        u.y = fmaxf(fmaf(u.y, s1, o1), 0.f);
                        u.z = fmaxf(fmaf(u.z, s2, o2), 0.f);
                        u.w = fmaxf(fmaf(u.w, s3, o3), 0.f);
                    }
                    acc.x += u.x; acc.y += u.y; acc.z += u.z; acc.w += u.w;
                }
            }
            xs[cg * 4 + 0][r] = acc.x;
            xs[cg * 4 + 1][r] = acc.y;
            xs[cg * 4 + 2][r] = acc.z;
            xs[cg * 4 + 3][r] = acc.w;
        }
    }
    __syncthreads();

    int tr = tid & 15, tc = tid >> 4;
    int r = tr * 4, c = tc * 4;
    float acc[4][4];

    // ---- GEMM1: relu(xs @ W1 + b1) ----
#pragma unroll
    for (int i = 0; i < 4; ++i)
#pragma unroll
        for (int j = 0; j < 4; ++j) acc[i][j] = 0.f;
#pragma unroll 8
    for (int k = 0; k < 64; ++k) {
        float4 xv = *reinterpret_cast<const float4*>(&xs[k][r]);
        float4 wv = *reinterpret_cast<const float4*>(&wsh[k * 64 + c]);
        float xa[4] = {xv.x, xv.y, xv.z, xv.w};
        float wa[4] = {wv.x, wv.y, wv.z, wv.w};
#pragma unroll
        for (int i = 0; i < 4; ++i)
#pragma unroll
            for (int j = 0; j < 4; ++j) acc[i][j] = fmaf(xa[i], wa[j], acc[i][j]);
    }
#pragma unroll
    for (int j = 0; j < 4; ++j) {
        float bj = bsh[c + j];
#pragma unroll
        for (int i = 0; i < 4; ++i) acc[i][j] = fmaxf(acc[i][j] + bj, 0.f);
    }
    __syncthreads();  // all reads of xs/wsh done

    // write h1 transposed into xs; hot-swap W2/b2
#pragma unroll
    for (int i = 0; i < 4; ++i)
#pragma unroll
        for (int j = 0; j < 4; ++j) xs[c + j][r + i] = acc[i][j];
    const float4* w24 = reinterpret_cast<const float4*>(w2);
#pragma unroll
    for (int i = 0; i < 4; ++i) wsh4[tid + i * 256] = w24[tid + i * 256];
    if (tid < 64) bsh[tid] = b2[tid];
    __syncthreads();

    // ---- GEMM2: relu(h1 @ W2 + b2) ----
#pragma unroll
    for (int i = 0; i < 4; ++i)
#pragma unroll
        for (int j = 0; j < 4; ++j) acc[i][j] = 0.f;
#pragma unroll 8
    for (int k = 0; k < 64; ++k) {
        float4 xv = *reinterpret_cast<const float4*>(&xs[k][r]);
        float4 wv = *reinterpret_cast<const float4*>(&wsh[k * 64 + c]);
        float xa[4] = {xv.x, xv.y, xv.z, xv.w};
        float wa[4] = {wv.x, wv.y, wv.z, wv.w};
#pragma unroll
        for (int i = 0; i < 4; ++i)
#pragma unroll
            for (int j = 0; j < 4; ++j) acc[i][j] = fmaf(xa[i], wa[j], acc[i][j]);
    }
#pragma unroll
    for (int j = 0; j < 4; ++j) {
        float bj = bsh[c + j];
#pragma unroll
        for (int i = 0; i < 4; ++i) acc[i][j] = fmaxf(acc[i][j] + bj, 0.f);
    }

    // store h + BN stats
#pragma unroll
    for (int i = 0; i < 4; ++i) {
        int row = r0 + r + i;
        if (row < N_NODES) {
            float4 o = make_float4(acc[i][0], acc[i][1], acc[i][2], acc[i][3]);
            *reinterpret_cast<float4*>(hout + (size_t)row * 64 + c) = o;
        }
    }
#pragma unroll
    for (int j = 0; j < 4; ++j) {
        float s = 0.f, q = 0.f;
#pragma unroll
        for (int i = 0; i < 4; ++i) {
            if (r0 + r + i < N_NODES) {
                s += acc[i][j];
                q += acc[i][j] * acc[i][j];
            }
        }
        atomicAdd(&sred[c + j], s);
        atomicAdd(&sred[64 + c + j], q);
    }
    __syncthreads();
    if (tid < 128) atomicAdd(&stats[tid], sred[tid]);
}

// ---------------------------------------------------------------------------
// out[N x 16] = bnrelu3(h) @ wl + bl
__global__ __launch_bounds__(256) void final_k(const float* __restrict__ hin,
                                               const float* __restrict__ pstats,
                                               const float* __restrict__ pg,
                                               const float* __restrict__ pbt,
                                               const float* __restrict__ wl,
                                               const float* __restrict__ bl,
                                               float* __restrict__ out) {
    __shared__ float xs[64][68];
    __shared__ float wsh[64 * 16];
    __shared__ float bsh[16];
    __shared__ float ssc[64], sof[64];
    int tid = threadIdx.x;
    int r0 = blockIdx.x * 64;

    if (tid < 64) {
        float mean = pstats[tid] * (1.f / N_NODES);
        float var = pstats[64 + tid] * (1.f / N_NODES) - mean * mean;
        float sc = pg[tid] * rsqrtf(var + BN_EPS);
        ssc[tid] = sc;
        sof[tid] = pbt[tid] - mean * sc;
    }
    reinterpret_cast<float4*>(wsh)[tid] = reinterpret_cast<const float4*>(wl)[tid];
    if (tid < 16) bsh[tid] = bl[tid];
    __syncthreads();

    {
        int rr = tid >> 4, cg = tid & 15;
#pragma unroll
        for (int i = 0; i < 4; ++i) {
            int r = rr + i * 16;
            float4 v = make_float4(0.f, 0.f, 0.f, 0.f);
            if (r0 + r < N_NODES) {
                v = reinterpret_cast<const float4*>(hin + (size_t)(r0 + r) * 64)[cg];
                int c = cg * 4;
                v.x = fmaxf(fmaf(v.x, ssc[c + 0], sof[c + 0]), 0.f);
                v.y = fmaxf(fmaf(v.y, ssc[c + 1], sof[c + 1]), 0.f);
                v.z = fmaxf(fmaf(v.z, ssc[c + 2], sof[c + 2]), 0.f);
                v.w = fmaxf(fmaf(v.w, ssc[c + 3], sof[c + 3]), 0.f);
            }
            xs[cg * 4 + 0][r] = v.x;
            xs[cg * 4 + 1][r] = v.y;
            xs[cg * 4 + 2][r] = v.z;
            xs[cg * 4 + 3][r] = v.w;
        }
    }
    __syncthreads();

    int tc = tid & 3, r = tid >> 2;
    int c = tc * 4;
    float acc0 = 0.f, acc1 = 0.f, acc2 = 0.f, acc3 = 0.f;
#pragma unroll 8
    for (int k = 0; k < 64; ++k) {
        float xv = xs[k][r];
        float4 wv = *reinterpret_cast<const float4*>(&wsh[k * 16 + c]);
        acc0 = fmaf(xv, wv.x, acc0);
        acc1 = fmaf(xv, wv.y, acc1);
        acc2 = fmaf(xv, wv.z, acc2);
        acc3 = fmaf(xv, wv.w, acc3);
    }
    int row = r0 + r;
    if (row < N_NODES) {
        float4 o = make_float4(acc0 + bsh[c], acc1 + bsh[c + 1], acc2 + bsh[c + 2], acc3 + bsh[c + 3]);
        *reinterpret_cast<float4*>(out + (size_t)row * 16 + c) = o;
    }
}

// ---------------------------------------------------------------------------
extern "C" void kernel_launch(void* const* d_in, const int* in_sizes, int n_in,
                              void* d_out, int out_size, void* d_ws, size_t ws_size,
                              hipStream_t stream) {
    const float* x = (const float*)d_in[0];
    const int* ei = (const int*)d_in[1];
    const int E = in_sizes[1] / 2;

    const float* eps[3] = {(const float*)d_in[2], (const float*)d_in[9], (const float*)d_in[16]};
    const float* w1[3]  = {(const float*)d_in[3], (const float*)d_in[10], (const float*)d_in[17]};
    const float* b1[3]  = {(const float*)d_in[4], (const float*)d_in[11], (const float*)d_in[18]};
    const float* w2[3]  = {(const float*)d_in[5], (const float*)d_in[12], (const float*)d_in[19]};
    const float* b2[3]  = {(const float*)d_in[6], (const float*)d_in[13], (const float*)d_in[20]};
    const float* g[3]   = {(const float*)d_in[7], (const float*)d_in[14], (const float*)d_in[21]};
    const float* bt[3]  = {(const float*)d_in[8], (const float*)d_in[15], (const float*)d_in[22]};
    const float* wl = (const float*)d_in[23];
    const float* bl = (const float*)d_in[24];

    // workspace layout
    float* ha    = (float*)d_ws;
    float* hb    = ha + (size_t)N_NODES * 64;
    float* stats = hb + (size_t)N_NODES * 64;
    int* gcnt    = (int*)(stats + 384);
    int* bbase   = gcnt + NB;
    int* gcursor = bbase + (NB + 1);
    int* row_ptr = gcursor + NB;
    int* tail    = row_ptr + (N_NODES + 1);
    size_t used  = (size_t)((char*)tail - (char*)d_ws);

    // two E-int buffers: csr_src (persists through layers) and part (build only)
    int* csr_src;
    int* part;
    if (used + 2 * (size_t)E * 4 <= ws_size) {
        csr_src = tail;
        part = csr_src + E;
    } else {
        // part lives in ws, csr_src in d_out (d_out = N*16 floats = E ints;
        // only final_k writes d_out, after the last layer_k consumed csr_src)
        part = tail;
        csr_src = (int*)d_out;
    }

    // ---- partition + CSR build (once) ----
    zero_misc_k<<<(NB + 255) / 256, 256, 0, stream>>>(stats, gcnt);
    histA_k<<<PART_BLOCKS, 256, 0, stream>>>(ei, gcnt, E);
    scanA_k<<<1, 256, 0, stream>>>(gcnt, bbase, gcursor);
    partA_k<<<PART_BLOCKS, 256, 0, stream>>>(ei, gcursor, part, E);
    sortB_k<<<NB, 256, 0, stream>>>(part, bbase, row_ptr, csr_src);

    // ---- 3 fused GIN layers ----
    layer_k<true><<<NB, 256, 0, stream>>>(x, nullptr, nullptr, nullptr, row_ptr, csr_src,
                                          eps[0], w1[0], b1[0], w2[0], b2[0], ha, stats + 0);
    layer_k<false><<<NB, 256, 0, stream>>>(ha, stats + 0, g[0], bt[0], row_ptr, csr_src,
                                           eps[1], w1[1], b1[1], w2[1], b2[1], hb, stats + 128);
    layer_k<false><<<NB, 256, 0, stream>>>(hb, stats + 128, g[1], bt[1], row_ptr, csr_src,
                                           eps[2], w1[2], b1[2], w2[2], b2[2], ha, stats + 256);

    // ---- final linear with BN3 fused ----
    final_k<<<NB, 256, 0, stream>>>(ha, stats + 256, g[2], bt[2], wl, bl, (float*)d_out);
}

// Round 5
// 436.152 us; speedup vs baseline: 4.5862x; 1.2674x over previous
//
#include <hip/hip_runtime.h>
#include <hip/hip_fp16.h>
#include <math.h>

#define N_NODES 100000
#define NB 1563              // ceil(N_NODES / 64) buckets of 64 dst nodes
#define BN_EPS 1e-5f
#define PART_BLOCKS 128

// ---------------------------------------------------------------------------
__global__ void zero_misc_k(float* stats, int* gcnt) {
    int gid = blockIdx.x * blockDim.x + threadIdx.x;
    if (gid < 384) stats[gid] = 0.f;
    if (gid < NB) gcnt[gid] = 0;
}

// x fp32 -> fp16 (4 elems per thread)
__global__ void tofp16_k(const float* __restrict__ x, __half* __restrict__ xh, int n4) {
    int gid = blockIdx.x * blockDim.x + threadIdx.x;
    if (gid >= n4) return;
    float4 v = reinterpret_cast<const float4*>(x)[gid];
    union { float2 f; __half2 h[2]; } u;
    u.h[0] = __float22half2_rn(make_float2(v.x, v.y));
    u.h[1] = __float22half2_rn(make_float2(v.z, v.w));
    reinterpret_cast<float2*>(xh)[gid] = u.f;
}

// per-bucket edge histogram (bucket = dst >> 6), block-aggregated in LDS
__global__ __launch_bounds__(256) void histA_k(const int* __restrict__ ei,
                                               int* __restrict__ gcnt, int E) {
    __shared__ int cnt[NB];
    for (int i = threadIdx.x; i < NB; i += 256) cnt[i] = 0;
    __syncthreads();
    int per = (E + gridDim.x - 1) / gridDim.x;
    int s0 = blockIdx.x * per, s1 = min(E, s0 + per);
    for (int e = s0 + threadIdx.x; e < s1; e += 256)
        atomicAdd(&cnt[ei[E + e] >> 6], 1);
    __syncthreads();
    for (int i = threadIdx.x; i < NB; i += 256)
        if (cnt[i]) atomicAdd(&gcnt[i], cnt[i]);
}

// exclusive scan of NB bucket counts (single block, 7 elems/thread)
__global__ __launch_bounds__(256) void scanA_k(const int* __restrict__ gcnt,
                                               int* __restrict__ bbase,
                                               int* __restrict__ gcursor) {
    __shared__ int tmp[256];
    int t = threadIdx.x;
    int v[7];
    int s = 0;
#pragma unroll
    for (int j = 0; j < 7; ++j) {
        int idx = t * 7 + j;
        v[j] = (idx < NB) ? gcnt[idx] : 0;
        s += v[j];
    }
    tmp[t] = s;
    __syncthreads();
    for (int off = 1; off < 256; off <<= 1) {
        int a = (t >= off) ? tmp[t - off] : 0;
        __syncthreads();
        tmp[t] += a;
        __syncthreads();
    }
    int run = tmp[t] - s;
#pragma unroll
    for (int j = 0; j < 7; ++j) {
        int idx = t * 7 + j;
        if (idx < NB) { bbase[idx] = run; gcursor[idx] = run; }
        run += v[j];
    }
    if (t == 255) bbase[NB] = run;  // == E
}

// bucket-partition edges: part[] entries are (dst&63)<<20 | src, bucket-contiguous
__global__ __launch_bounds__(256) void partA_k(const int* __restrict__ ei,
                                               int* __restrict__ gcursor,
                                               int* __restrict__ part, int E) {
    __shared__ int cnt[NB];
    __shared__ int base[NB];
    for (int i = threadIdx.x; i < NB; i += 256) cnt[i] = 0;
    __syncthreads();
    int per = (E + gridDim.x - 1) / gridDim.x;
    int s0 = blockIdx.x * per, s1 = min(E, s0 + per);
    for (int e = s0 + threadIdx.x; e < s1; e += 256)
        atomicAdd(&cnt[ei[E + e] >> 6], 1);
    __syncthreads();
    for (int i = threadIdx.x; i < NB; i += 256) {
        int c = cnt[i];
        base[i] = c ? atomicAdd(&gcursor[i], c) : 0;
    }
    __syncthreads();
    for (int i = threadIdx.x; i < NB; i += 256) cnt[i] = 0;
    __syncthreads();
    for (int e = s0 + threadIdx.x; e < s1; e += 256) {
        int s = ei[e], d = ei[E + e];
        int b = d >> 6, dl = d & 63;
        int lo = atomicAdd(&cnt[b], 1);
        part[base[b] + lo] = (dl << 20) | s;
    }
}

// per-bucket LDS counting sort: part (bucket-contiguous) -> csr_src (node-ordered)
__global__ __launch_bounds__(256) void sortB_k(const int* __restrict__ part,
                                               const int* __restrict__ bbase,
                                               int* __restrict__ row_ptr,
                                               int* __restrict__ csr_src) {
    __shared__ int cnt[64];
    __shared__ int cur[64];
    int b = blockIdx.x;
    int t = threadIdx.x;
    int e0 = bbase[b], e1 = bbase[b + 1];
    if (t < 64) cnt[t] = 0;
    __syncthreads();
    for (int i = e0 + t; i < e1; i += 256) atomicAdd(&cnt[(part[i] >> 20) & 63], 1);
    __syncthreads();
    if (t < 64) {
        int c = cnt[t];
        int v = c;
        for (int off = 1; off < 64; off <<= 1) {
            int u = __shfl_up(v, off, 64);
            if (t >= off) v += u;
        }
        int excl = v - c;
        int node = b * 64 + t;
        if (node <= N_NODES) row_ptr[node] = e0 + excl;
        cur[t] = e0 + excl;
    }
    __syncthreads();
    for (int i = e0 + t; i < e1; i += 256) {
        int u = part[i];
        int dl = (u >> 20) & 63;
        int pos = atomicAdd(&cur[dl], 1);
        csr_src[pos] = u & 0xFFFFF;
    }
}

// load 4 channels (cg-th half4) of a fp16 row as fp32
__device__ __forceinline__ float4 ld_row16(const __half* __restrict__ base, int cg) {
    float2 raw = reinterpret_cast<const float2*>(base)[cg];
    __half2 h01 = *reinterpret_cast<const __half2*>(&raw.x);
    __half2 h23 = *reinterpret_cast<const __half2*>(&raw.y);
    float2 f01 = __half22float2(h01);
    float2 f23 = __half22float2(h23);
    return make_float4(f01.x, f01.y, f23.x, f23.y);
}

// ---------------------------------------------------------------------------
// Fused GIN layer: block = 64 dst nodes. fp16 h storage, fp32 compute.
template <bool FIRST>
__global__ __launch_bounds__(256, 6) void layer_k(
    const __half* __restrict__ hin, const float* __restrict__ pstats,
    const float* __restrict__ pg, const float* __restrict__ pbt,
    const int* __restrict__ row_ptr, const int* __restrict__ csr_src,
    const float* __restrict__ epsp,
    const float* __restrict__ w1, const float* __restrict__ b1,
    const float* __restrict__ w2, const float* __restrict__ b2,
    __half* __restrict__ hout, float* __restrict__ stats) {
    __shared__ float xs[64][68];   // xs[channel][row]
    __shared__ float ssc[64], sof[64];
    __shared__ float sred[128];

    int tid = threadIdx.x;
    int r0 = blockIdx.x * 64;

    if (tid < 64) {
        if (FIRST) {
            ssc[tid] = 1.f;
            sof[tid] = 0.f;
        } else {
            float mean = pstats[tid] * (1.f / N_NODES);
            float var = pstats[64 + tid] * (1.f / N_NODES) - mean * mean;
            float sc = pg[tid] * rsqrtf(var + BN_EPS);
            ssc[tid] = sc;
            sof[tid] = pbt[tid] - mean * sc;
        }
    }
    if (tid < 128) sred[tid] = 0.f;
    __syncthreads();  // ssc/sof ready for gather

    float eps1 = 1.0f + *epsp;
    int cg = tid & 15;
    float s0 = ssc[cg * 4 + 0], s1 = ssc[cg * 4 + 1];
    float s2 = ssc[cg * 4 + 2], s3 = ssc[cg * 4 + 3];
    float o0 = sof[cg * 4 + 0], o1 = sof[cg * 4 + 1];
    float o2 = sof[cg * 4 + 2], o3 = sof[cg * 4 + 3];

    // Phase A: register gather, 16 lanes per node, 4 nodes per lane-group
    {
        int rr = tid >> 4;
#pragma unroll
        for (int i = 0; i < 4; ++i) {
            int r = rr + i * 16;
            int node = r0 + r;
            float4 acc = make_float4(0.f, 0.f, 0.f, 0.f);
            if (node < N_NODES) {
                float4 v = ld_row16(hin + (size_t)node * 64, cg);
                if (!FIRST) {
                    v.x = fmaxf(fmaf(v.x, s0, o0), 0.f);
                    v.y = fmaxf(fmaf(v.y, s1, o1), 0.f);
                    v.z = fmaxf(fmaf(v.z, s2, o2), 0.f);
                    v.w = fmaxf(fmaf(v.w, s3, o3), 0.f);
                }
                acc.x = v.x * eps1; acc.y = v.y * eps1;
                acc.z = v.z * eps1; acc.w = v.w * eps1;
                int j0 = row_ptr[node], j1 = row_ptr[node + 1];
                for (int j = j0; j < j1; ++j) {
                    int sidx = csr_src[j];
                    float4 u = ld_row16(hin + (size_t)sidx * 64, cg);
                    if (!FIRST) {
                        u.x = fmaxf(fmaf(u.x, s0, o0), 0.f);
                        u.y = fmaxf(fmaf(u.y, s1, o1), 0.f);
                        u.z = fmaxf(fmaf(u.z, s2, o2), 0.f);
                        u.w = fmaxf(fmaf(u.w, s3, o3), 0.f);
                    }
                    acc.x += u.x; acc.y += u.y; acc.z += u.z; acc.w += u.w;
                }
            }
            xs[cg * 4 + 0][r] = acc.x;
            xs[cg * 4 + 1][r] = acc.y;
            xs[cg * 4 + 2][r] = acc.z;
            xs[cg * 4 + 3][r] = acc.w;
        }
    }
    __syncthreads();

    int tr = tid & 15, tc = tid >> 4;
    int r = tr * 4, c = tc * 4;
    float acc[4][4];
    const float4* w14 = reinterpret_cast<const float4*>(w1);
    const float4* w24 = reinterpret_cast<const float4*>(w2);

    // ---- GEMM1: relu(xs @ W1 + b1), W1 streamed from global (L1 broadcast) ----
#pragma unroll
    for (int i = 0; i < 4; ++i)
#pragma unroll
        for (int j = 0; j < 4; ++j) acc[i][j] = 0.f;
#pragma unroll 4
    for (int k = 0; k < 64; ++k) {
        float4 xv = *reinterpret_cast<const float4*>(&xs[k][r]);
        float4 wv = w14[k * 16 + tc];
        float xa[4] = {xv.x, xv.y, xv.z, xv.w};
        float wa[4] = {wv.x, wv.y, wv.z, wv.w};
#pragma unroll
        for (int i = 0; i < 4; ++i)
#pragma unroll
            for (int j = 0; j < 4; ++j) acc[i][j] = fmaf(xa[i], wa[j], acc[i][j]);
    }
    {
        float4 bv = reinterpret_cast<const float4*>(b1)[tc];
        float ba[4] = {bv.x, bv.y, bv.z, bv.w};
#pragma unroll
        for (int j = 0; j < 4; ++j)
#pragma unroll
            for (int i = 0; i < 4; ++i) acc[i][j] = fmaxf(acc[i][j] + ba[j], 0.f);
    }
    __syncthreads();  // all reads of xs done

    // write h1 transposed into xs
#pragma unroll
    for (int i = 0; i < 4; ++i)
#pragma unroll
        for (int j = 0; j < 4; ++j) xs[c + j][r + i] = acc[i][j];
    __syncthreads();

    // ---- GEMM2: relu(h1 @ W2 + b2) ----
#pragma unroll
    for (int i = 0; i < 4; ++i)
#pragma unroll
        for (int j = 0; j < 4; ++j) acc[i][j] = 0.f;
#pragma unroll 4
    for (int k = 0; k < 64; ++k) {
        float4 xv = *reinterpret_cast<const float4*>(&xs[k][r]);
        float4 wv = w24[k * 16 + tc];
        float xa[4] = {xv.x, xv.y, xv.z, xv.w};
        float wa[4] = {wv.x, wv.y, wv.z, wv.w};
#pragma unroll
        for (int i = 0; i < 4; ++i)
#pragma unroll
            for (int j = 0; j < 4; ++j) acc[i][j] = fmaf(xa[i], wa[j], acc[i][j]);
    }
    {
        float4 bv = reinterpret_cast<const float4*>(b2)[tc];
        float ba[4] = {bv.x, bv.y, bv.z, bv.w};
#pragma unroll
        for (int j = 0; j < 4; ++j)
#pragma unroll
            for (int i = 0; i < 4; ++i) acc[i][j] = fmaxf(acc[i][j] + ba[j], 0.f);
    }

    // store h (fp16) + BN stats (fp32)
#pragma unroll
    for (int i = 0; i < 4; ++i) {
        int row = r0 + r + i;
        if (row < N_NODES) {
            union { float2 f; __half2 h[2]; } u;
            u.h[0] = __float22half2_rn(make_float2(acc[i][0], acc[i][1]));
            u.h[1] = __float22half2_rn(make_float2(acc[i][2], acc[i][3]));
            *reinterpret_cast<float2*>(hout + (size_t)row * 64 + c) = u.f;
        }
    }
#pragma unroll
    for (int j = 0; j < 4; ++j) {
        float s = 0.f, q = 0.f;
#pragma unroll
        for (int i = 0; i < 4; ++i) {
            if (r0 + r + i < N_NODES) {
                s += acc[i][j];
                q += acc[i][j] * acc[i][j];
            }
        }
        atomicAdd(&sred[c + j], s);
        atomicAdd(&sred[64 + c + j], q);
    }
    __syncthreads();
    if (tid < 128) atomicAdd(&stats[tid], sred[tid]);
}

// ---------------------------------------------------------------------------
// out[N x 16] = bnrelu3(h) @ wl + bl   (h in fp16)
__global__ __launch_bounds__(256) void final_k(const __half* __restrict__ hin,
                                               const float* __restrict__ pstats,
                                               const float* __restrict__ pg,
                                               const float* __restrict__ pbt,
                                               const float* __restrict__ wl,
                                               const float* __restrict__ bl,
                                               float* __restrict__ out) {
    __shared__ float xs[64][68];
    __shared__ float wsh[64 * 16];
    __shared__ float bsh[16];
    __shared__ float ssc[64], sof[64];
    int tid = threadIdx.x;
    int r0 = blockIdx.x * 64;

    if (tid < 64) {
        float mean = pstats[tid] * (1.f / N_NODES);
        float var = pstats[64 + tid] * (1.f / N_NODES) - mean * mean;
        float sc = pg[tid] * rsqrtf(var + BN_EPS);
        ssc[tid] = sc;
        sof[tid] = pbt[tid] - mean * sc;
    }
    reinterpret_cast<float4*>(wsh)[tid] = reinterpret_cast<const float4*>(wl)[tid];
    if (tid < 16) bsh[tid] = bl[tid];
    __syncthreads();

    {
        int rr = tid >> 4, cg = tid & 15;
#pragma unroll
        for (int i = 0; i < 4; ++i) {
            int r = rr + i * 16;
            float4 v = make_float4(0.f, 0.f, 0.f, 0.f);
            if (r0 + r < N_NODES) {
                v = ld_row16(hin + (size_t)(r0 + r) * 64, cg);
                int c = cg * 4;
                v.x = fmaxf(fmaf(v.x, ssc[c + 0], sof[c + 0]), 0.f);
                v.y = fmaxf(fmaf(v.y, ssc[c + 1], sof[c + 1]), 0.f);
                v.z = fmaxf(fmaf(v.z, ssc[c + 2], sof[c + 2]), 0.f);
                v.w = fmaxf(fmaf(v.w, ssc[c + 3], sof[c + 3]), 0.f);
            }
            xs[cg * 4 + 0][r] = v.x;
            xs[cg * 4 + 1][r] = v.y;
            xs[cg * 4 + 2][r] = v.z;
            xs[cg * 4 + 3][r] = v.w;
        }
    }
    __syncthreads();

    int tc = tid & 3, r = tid >> 2;
    int c = tc * 4;
    float acc0 = 0.f, acc1 = 0.f, acc2 = 0.f, acc3 = 0.f;
#pragma unroll 8
    for (int k = 0; k < 64; ++k) {
        float xv = xs[k][r];
        float4 wv = *reinterpret_cast<const float4*>(&wsh[k * 16 + c]);
        acc0 = fmaf(xv, wv.x, acc0);
        acc1 = fmaf(xv, wv.y, acc1);
        acc2 = fmaf(xv, wv.z, acc2);
        acc3 = fmaf(xv, wv.w, acc3);
    }
    int row = r0 + r;
    if (row < N_NODES) {
        float4 o = make_float4(acc0 + bsh[c], acc1 + bsh[c + 1], acc2 + bsh[c + 2], acc3 + bsh[c + 3]);
        *reinterpret_cast<float4*>(out + (size_t)row * 16 + c) = o;
    }
}

// ---------------------------------------------------------------------------
extern "C" void kernel_launch(void* const* d_in, const int* in_sizes, int n_in,
                              void* d_out, int out_size, void* d_ws, size_t ws_size,
                              hipStream_t stream) {
    const float* x = (const float*)d_in[0];
    const int* ei = (const int*)d_in[1];
    const int E = in_sizes[1] / 2;

    const float* eps[3] = {(const float*)d_in[2], (const float*)d_in[9], (const float*)d_in[16]};
    const float* w1[3]  = {(const float*)d_in[3], (const float*)d_in[10], (const float*)d_in[17]};
    const float* b1[3]  = {(const float*)d_in[4], (const float*)d_in[11], (const float*)d_in[18]};
    const float* w2[3]  = {(const float*)d_in[5], (const float*)d_in[12], (const float*)d_in[19]};
    const float* b2[3]  = {(const float*)d_in[6], (const float*)d_in[13], (const float*)d_in[20]};
    const float* g[3]   = {(const float*)d_in[7], (const float*)d_in[14], (const float*)d_in[21]};
    const float* bt[3]  = {(const float*)d_in[8], (const float*)d_in[15], (const float*)d_in[22]};
    const float* wl = (const float*)d_in[23];
    const float* bl = (const float*)d_in[24];

    // workspace layout (fp16 h buffers)
    __half* xh   = (__half*)d_ws;                       // N*64 fp16
    __half* ha   = xh + (size_t)N_NODES * 64;
    __half* hb   = ha + (size_t)N_NODES * 64;
    float* stats = (float*)(hb + (size_t)N_NODES * 64);
    int* gcnt    = (int*)(stats + 384);
    int* bbase   = gcnt + NB;
    int* gcursor = bbase + (NB + 1);
    int* row_ptr = gcursor + NB;
    int* tail    = row_ptr + (N_NODES + 1);
    size_t used  = (size_t)((char*)tail - (char*)d_ws);

    int* csr_src;
    int* part;
    if (used + 2 * (size_t)E * 4 <= ws_size) {
        csr_src = tail;
        part = csr_src + E;
    } else {
        part = tail;
        csr_src = (int*)d_out;  // consumed before final_k writes d_out
    }

    const int n4 = N_NODES * 16;

    // ---- partition + CSR build + x->fp16 (once) ----
    zero_misc_k<<<(NB + 255) / 256, 256, 0, stream>>>(stats, gcnt);
    tofp16_k<<<(n4 + 255) / 256, 256, 0, stream>>>(x, xh, n4);
    histA_k<<<PART_BLOCKS, 256, 0, stream>>>(ei, gcnt, E);
    scanA_k<<<1, 256, 0, stream>>>(gcnt, bbase, gcursor);
    partA_k<<<PART_BLOCKS, 256, 0, stream>>>(ei, gcursor, part, E);
    sortB_k<<<NB, 256, 0, stream>>>(part, bbase, row_ptr, csr_src);

    // ---- 3 fused GIN layers ----
    layer_k<true><<<NB, 256, 0, stream>>>(xh, nullptr, nullptr, nullptr, row_ptr, csr_src,
                                          eps[0], w1[0], b1[0], w2[0], b2[0], ha, stats + 0);
    layer_k<false><<<NB, 256, 0, stream>>>(ha, stats + 0, g[0], bt[0], row_ptr, csr_src,
                                           eps[1], w1[1], b1[1], w2[1], b2[1], hb, stats + 128);
    layer_k<false><<<NB, 256, 0, stream>>>(hb, stats + 128, g[1], bt[1], row_ptr, csr_src,
                                           eps[2], w1[2], b1[2], w2[2], b2[2], ha, stats + 256);

    // ---- final linear with BN3 fused ----
    final_k<<<NB, 256, 0, stream>>>(ha, stats + 256, g[2], bt[2], wl, bl, (float*)d_out);
}

// Round 6
// 373.197 us; speedup vs baseline: 5.3599x; 1.1687x over previous
//
#include <hip/hip_runtime.h>
#include <hip/hip_fp16.h>
#include <math.h>

#define N_NODES 100000
#define NB 1563              // ceil(N_NODES / 64) buckets of 64 dst nodes
#define BN_EPS 1e-5f
#define PART_BLOCKS 128

// ---------------------------------------------------------------------------
__global__ void zero_misc_k(float* stats, int* gcnt) {
    int gid = blockIdx.x * blockDim.x + threadIdx.x;
    if (gid < 384) stats[gid] = 0.f;
    if (gid < NB) gcnt[gid] = 0;
}

// x fp32 -> fp16 (4 elems per thread)
__global__ void tofp16_k(const float* __restrict__ x, __half* __restrict__ xh, int n4) {
    int gid = blockIdx.x * blockDim.x + threadIdx.x;
    if (gid >= n4) return;
    float4 v = reinterpret_cast<const float4*>(x)[gid];
    union { float2 f; __half2 h[2]; } u;
    u.h[0] = __float22half2_rn(make_float2(v.x, v.y));
    u.h[1] = __float22half2_rn(make_float2(v.z, v.w));
    reinterpret_cast<float2*>(xh)[gid] = u.f;
}

// per-bucket edge histogram (bucket = dst >> 6), block-aggregated in LDS
__global__ __launch_bounds__(256) void histA_k(const int* __restrict__ ei,
                                               int* __restrict__ gcnt, int E) {
    __shared__ int cnt[NB];
    for (int i = threadIdx.x; i < NB; i += 256) cnt[i] = 0;
    __syncthreads();
    int per = (E + gridDim.x - 1) / gridDim.x;
    int s0 = blockIdx.x * per, s1 = min(E, s0 + per);
    for (int e = s0 + threadIdx.x; e < s1; e += 256)
        atomicAdd(&cnt[ei[E + e] >> 6], 1);
    __syncthreads();
    for (int i = threadIdx.x; i < NB; i += 256)
        if (cnt[i]) atomicAdd(&gcnt[i], cnt[i]);
}

// exclusive scan of NB bucket counts (single block, 7 elems/thread)
__global__ __launch_bounds__(256) void scanA_k(const int* __restrict__ gcnt,
                                               int* __restrict__ bbase,
                                               int* __restrict__ gcursor) {
    __shared__ int tmp[256];
    int t = threadIdx.x;
    int v[7];
    int s = 0;
#pragma unroll
    for (int j = 0; j < 7; ++j) {
        int idx = t * 7 + j;
        v[j] = (idx < NB) ? gcnt[idx] : 0;
        s += v[j];
    }
    tmp[t] = s;
    __syncthreads();
    for (int off = 1; off < 256; off <<= 1) {
        int a = (t >= off) ? tmp[t - off] : 0;
        __syncthreads();
        tmp[t] += a;
        __syncthreads();
    }
    int run = tmp[t] - s;
#pragma unroll
    for (int j = 0; j < 7; ++j) {
        int idx = t * 7 + j;
        if (idx < NB) { bbase[idx] = run; gcursor[idx] = run; }
        run += v[j];
    }
    if (t == 255) bbase[NB] = run;  // == E
}

// bucket-partition edges: part[] entries are (dst&63)<<20 | src, bucket-contiguous
__global__ __launch_bounds__(256) void partA_k(const int* __restrict__ ei,
                                               int* __restrict__ gcursor,
                                               int* __restrict__ part, int E) {
    __shared__ int cnt[NB];
    __shared__ int base[NB];
    for (int i = threadIdx.x; i < NB; i += 256) cnt[i] = 0;
    __syncthreads();
    int per = (E + gridDim.x - 1) / gridDim.x;
    int s0 = blockIdx.x * per, s1 = min(E, s0 + per);
    for (int e = s0 + threadIdx.x; e < s1; e += 256)
        atomicAdd(&cnt[ei[E + e] >> 6], 1);
    __syncthreads();
    for (int i = threadIdx.x; i < NB; i += 256) {
        int c = cnt[i];
        base[i] = c ? atomicAdd(&gcursor[i], c) : 0;
    }
    __syncthreads();
    for (int i = threadIdx.x; i < NB; i += 256) cnt[i] = 0;
    __syncthreads();
    for (int e = s0 + threadIdx.x; e < s1; e += 256) {
        int s = ei[e], d = ei[E + e];
        int b = d >> 6, dl = d & 63;
        int lo = atomicAdd(&cnt[b], 1);
        part[base[b] + lo] = (dl << 20) | s;
    }
}

// per-bucket LDS counting sort: part (bucket-contiguous) -> csr_src (node-ordered)
__global__ __launch_bounds__(256) void sortB_k(const int* __restrict__ part,
                                               const int* __restrict__ bbase,
                                               int* __restrict__ row_ptr,
                                               int* __restrict__ csr_src) {
    __shared__ int cnt[64];
    __shared__ int cur[64];
    int b = blockIdx.x;
    int t = threadIdx.x;
    int e0 = bbase[b], e1 = bbase[b + 1];
    if (t < 64) cnt[t] = 0;
    __syncthreads();
    for (int i = e0 + t; i < e1; i += 256) atomicAdd(&cnt[(part[i] >> 20) & 63], 1);
    __syncthreads();
    if (t < 64) {
        int c = cnt[t];
        int v = c;
        for (int off = 1; off < 64; off <<= 1) {
            int u = __shfl_up(v, off, 64);
            if (t >= off) v += u;
        }
        int excl = v - c;
        int node = b * 64 + t;
        if (node <= N_NODES) row_ptr[node] = e0 + excl;
        cur[t] = e0 + excl;
    }
    __syncthreads();
    for (int i = e0 + t; i < e1; i += 256) {
        int u = part[i];
        int dl = (u >> 20) & 63;
        int pos = atomicAdd(&cur[dl], 1);
        csr_src[pos] = u & 0xFFFFF;
    }
}

// load 4 channels (cg-th half4) of a fp16 row as fp32
__device__ __forceinline__ float4 ld_row16(const __half* __restrict__ base, int cg) {
    float2 raw = reinterpret_cast<const float2*>(base)[cg];
    __half2 h01 = *reinterpret_cast<const __half2*>(&raw.x);
    __half2 h23 = *reinterpret_cast<const __half2*>(&raw.y);
    float2 f01 = __half22float2(h01);
    float2 f23 = __half22float2(h23);
    return make_float4(f01.x, f01.y, f23.x, f23.y);
}

// ---------------------------------------------------------------------------
// Fused GIN layer: block = 64 dst nodes. fp16 h storage, fp32 compute.
// Gather is software-pipelined: 4 neighbor rows in flight per lane.
template <bool FIRST>
__global__ __launch_bounds__(256, 6) void layer_k(
    const __half* __restrict__ hin, const float* __restrict__ pstats,
    const float* __restrict__ pg, const float* __restrict__ pbt,
    const int* __restrict__ row_ptr, const int* __restrict__ csr_src,
    const float* __restrict__ epsp,
    const float* __restrict__ w1, const float* __restrict__ b1,
    const float* __restrict__ w2, const float* __restrict__ b2,
    __half* __restrict__ hout, float* __restrict__ stats) {
    __shared__ float xs[64][68];   // xs[channel][row]
    __shared__ float ssc[64], sof[64];
    __shared__ float sred[128];

    int tid = threadIdx.x;
    int r0 = blockIdx.x * 64;

    if (tid < 64) {
        if (FIRST) {
            ssc[tid] = 1.f;
            sof[tid] = 0.f;
        } else {
            float mean = pstats[tid] * (1.f / N_NODES);
            float var = pstats[64 + tid] * (1.f / N_NODES) - mean * mean;
            float sc = pg[tid] * rsqrtf(var + BN_EPS);
            ssc[tid] = sc;
            sof[tid] = pbt[tid] - mean * sc;
        }
    }
    if (tid < 128) sred[tid] = 0.f;
    __syncthreads();  // ssc/sof ready for gather

    float eps1 = 1.0f + *epsp;
    int cg = tid & 15;
    float s0 = ssc[cg * 4 + 0], s1 = ssc[cg * 4 + 1];
    float s2 = ssc[cg * 4 + 2], s3 = ssc[cg * 4 + 3];
    float o0 = sof[cg * 4 + 0], o1 = sof[cg * 4 + 1];
    float o2 = sof[cg * 4 + 2], o3 = sof[cg * 4 + 3];

#define BNRELU(u)                                   \
    if (!FIRST) {                                   \
        u.x = fmaxf(fmaf(u.x, s0, o0), 0.f);        \
        u.y = fmaxf(fmaf(u.y, s1, o1), 0.f);        \
        u.z = fmaxf(fmaf(u.z, s2, o2), 0.f);        \
        u.w = fmaxf(fmaf(u.w, s3, o3), 0.f);        \
    }

    // Phase A: register gather, 16 lanes per node, 4 nodes per lane-group.
    {
        int rr = tid >> 4;
#pragma unroll
        for (int i = 0; i < 4; ++i) {
            int r = rr + i * 16;
            int node = r0 + r;
            float4 acc = make_float4(0.f, 0.f, 0.f, 0.f);
            if (node < N_NODES) {
                float4 v = ld_row16(hin + (size_t)node * 64, cg);
                BNRELU(v);
                acc.x = v.x * eps1; acc.y = v.y * eps1;
                acc.z = v.z * eps1; acc.w = v.w * eps1;
                int j0 = row_ptr[node], j1 = row_ptr[node + 1];
                int j = j0;
                // 4-deep software pipeline: 4 independent row loads in flight
                for (; j + 4 <= j1; j += 4) {
                    int ia = csr_src[j + 0];
                    int ib = csr_src[j + 1];
                    int ic = csr_src[j + 2];
                    int id = csr_src[j + 3];
                    float4 ua = ld_row16(hin + (size_t)ia * 64, cg);
                    float4 ub = ld_row16(hin + (size_t)ib * 64, cg);
                    float4 uc = ld_row16(hin + (size_t)ic * 64, cg);
                    float4 ud = ld_row16(hin + (size_t)id * 64, cg);
                    BNRELU(ua); BNRELU(ub); BNRELU(uc); BNRELU(ud);
                    acc.x += ua.x + ub.x + uc.x + ud.x;
                    acc.y += ua.y + ub.y + uc.y + ud.y;
                    acc.z += ua.z + ub.z + uc.z + ud.z;
                    acc.w += ua.w + ub.w + uc.w + ud.w;
                }
                for (; j < j1; ++j) {
                    int sidx = csr_src[j];
                    float4 u = ld_row16(hin + (size_t)sidx * 64, cg);
                    BNRELU(u);
                    acc.x += u.x; acc.y += u.y; acc.z += u.z; acc.w += u.w;
                }
            }
            xs[cg * 4 + 0][r] = acc.x;
            xs[cg * 4 + 1][r] = acc.y;
            xs[cg * 4 + 2][r] = acc.z;
            xs[cg * 4 + 3][r] = acc.w;
        }
    }
#undef BNRELU
    __syncthreads();

    int tr = tid & 15, tc = tid >> 4;
    int r = tr * 4, c = tc * 4;
    float acc[4][4];
    const float4* w14 = reinterpret_cast<const float4*>(w1);
    const float4* w24 = reinterpret_cast<const float4*>(w2);

    // ---- GEMM1: relu(xs @ W1 + b1), W1 streamed from global (L1 broadcast) ----
#pragma unroll
    for (int i = 0; i < 4; ++i)
#pragma unroll
        for (int j = 0; j < 4; ++j) acc[i][j] = 0.f;
#pragma unroll 4
    for (int k = 0; k < 64; ++k) {
        float4 xv = *reinterpret_cast<const float4*>(&xs[k][r]);
        float4 wv = w14[k * 16 + tc];
        float xa[4] = {xv.x, xv.y, xv.z, xv.w};
        float wa[4] = {wv.x, wv.y, wv.z, wv.w};
#pragma unroll
        for (int i = 0; i < 4; ++i)
#pragma unroll
            for (int j = 0; j < 4; ++j) acc[i][j] = fmaf(xa[i], wa[j], acc[i][j]);
    }
    {
        float4 bv = reinterpret_cast<const float4*>(b1)[tc];
        float ba[4] = {bv.x, bv.y, bv.z, bv.w};
#pragma unroll
        for (int j = 0; j < 4; ++j)
#pragma unroll
            for (int i = 0; i < 4; ++i) acc[i][j] = fmaxf(acc[i][j] + ba[j], 0.f);
    }
    __syncthreads();  // all reads of xs done

    // write h1 transposed into xs
#pragma unroll
    for (int i = 0; i < 4; ++i)
#pragma unroll
        for (int j = 0; j < 4; ++j) xs[c + j][r + i] = acc[i][j];
    __syncthreads();

    // ---- GEMM2: relu(h1 @ W2 + b2) ----
#pragma unroll
    for (int i = 0; i < 4; ++i)
#pragma unroll
        for (int j = 0; j < 4; ++j) acc[i][j] = 0.f;
#pragma unroll 4
    for (int k = 0; k < 64; ++k) {
        float4 xv = *reinterpret_cast<const float4*>(&xs[k][r]);
        float4 wv = w24[k * 16 + tc];
        float xa[4] = {xv.x, xv.y, xv.z, xv.w};
        float wa[4] = {wv.x, wv.y, wv.z, wv.w};
#pragma unroll
        for (int i = 0; i < 4; ++i)
#pragma unroll
            for (int j = 0; j < 4; ++j) acc[i][j] = fmaf(xa[i], wa[j], acc[i][j]);
    }
    {
        float4 bv = reinterpret_cast<const float4*>(b2)[tc];
        float ba[4] = {bv.x, bv.y, bv.z, bv.w};
#pragma unroll
        for (int j = 0; j < 4; ++j)
#pragma unroll
            for (int i = 0; i < 4; ++i) acc[i][j] = fmaxf(acc[i][j] + ba[j], 0.f);
    }

    // store h (fp16) + BN stats (fp32)
#pragma unroll
    for (int i = 0; i < 4; ++i) {
        int row = r0 + r + i;
        if (row < N_NODES) {
            union { float2 f; __half2 h[2]; } u;
            u.h[0] = __float22half2_rn(make_float2(acc[i][0], acc[i][1]));
            u.h[1] = __float22half2_rn(make_float2(acc[i][2], acc[i][3]));
            *reinterpret_cast<float2*>(hout + (size_t)row * 64 + c) = u.f;
        }
    }
#pragma unroll
    for (int j = 0; j < 4; ++j) {
        float s = 0.f, q = 0.f;
#pragma unroll
        for (int i = 0; i < 4; ++i) {
            if (r0 + r + i < N_NODES) {
                s += acc[i][j];
                q += acc[i][j] * acc[i][j];
            }
        }
        atomicAdd(&sred[c + j], s);
        atomicAdd(&sred[64 + c + j], q);
    }
    __syncthreads();
    if (tid < 128) atomicAdd(&stats[tid], sred[tid]);
}

// ---------------------------------------------------------------------------
// out[N x 16] = bnrelu3(h) @ wl + bl   (h in fp16)
__global__ __launch_bounds__(256) void final_k(const __half* __restrict__ hin,
                                               const float* __restrict__ pstats,
                                               const float* __restrict__ pg,
                                               const float* __restrict__ pbt,
                                               const float* __restrict__ wl,
                                               const float* __restrict__ bl,
                                               float* __restrict__ out) {
    __shared__ float xs[64][68];
    __shared__ float wsh[64 * 16];
    __shared__ float bsh[16];
    __shared__ float ssc[64], sof[64];
    int tid = threadIdx.x;
    int r0 = blockIdx.x * 64;

    if (tid < 64) {
        float mean = pstats[tid] * (1.f / N_NODES);
        float var = pstats[64 + tid] * (1.f / N_NODES) - mean * mean;
        float sc = pg[tid] * rsqrtf(var + BN_EPS);
        ssc[tid] = sc;
        sof[tid] = pbt[tid] - mean * sc;
    }
    reinterpret_cast<float4*>(wsh)[tid] = reinterpret_cast<const float4*>(wl)[tid];
    if (tid < 16) bsh[tid] = bl[tid];
    __syncthreads();

    {
        int rr = tid >> 4, cg = tid & 15;
#pragma unroll
        for (int i = 0; i < 4; ++i) {
            int r = rr + i * 16;
            float4 v = make_float4(0.f, 0.f, 0.f, 0.f);
            if (r0 + r < N_NODES) {
                v = ld_row16(hin + (size_t)(r0 + r) * 64, cg);
                int c = cg * 4;
                v.x = fmaxf(fmaf(v.x, ssc[c + 0], sof[c + 0]), 0.f);
                v.y = fmaxf(fmaf(v.y, ssc[c + 1], sof[c + 1]), 0.f);
                v.z = fmaxf(fmaf(v.z, ssc[c + 2], sof[c + 2]), 0.f);
                v.w = fmaxf(fmaf(v.w, ssc[c + 3], sof[c + 3]), 0.f);
            }
            xs[cg * 4 + 0][r] = v.x;
            xs[cg * 4 + 1][r] = v.y;
            xs[cg * 4 + 2][r] = v.z;
            xs[cg * 4 + 3][r] = v.w;
        }
    }
    __syncthreads();

    int tc = tid & 3, r = tid >> 2;
    int c = tc * 4;
    float acc0 = 0.f, acc1 = 0.f, acc2 = 0.f, acc3 = 0.f;
#pragma unroll 8
    for (int k = 0; k < 64; ++k) {
        float xv = xs[k][r];
        float4 wv = *reinterpret_cast<const float4*>(&wsh[k * 16 + c]);
        acc0 = fmaf(xv, wv.x, acc0);
        acc1 = fmaf(xv, wv.y, acc1);
        acc2 = fmaf(xv, wv.z, acc2);
        acc3 = fmaf(xv, wv.w, acc3);
    }
    int row = r0 + r;
    if (row < N_NODES) {
        float4 o = make_float4(acc0 + bsh[c], acc1 + bsh[c + 1], acc2 + bsh[c + 2], acc3 + bsh[c + 3]);
        *reinterpret_cast<float4*>(out + (size_t)row * 16 + c) = o;
    }
}

// ---------------------------------------------------------------------------
extern "C" void kernel_launch(void* const* d_in, const int* in_sizes, int n_in,
                              void* d_out, int out_size, void* d_ws, size_t ws_size,
                              hipStream_t stream) {
    const float* x = (const float*)d_in[0];
    const int* ei = (const int*)d_in[1];
    const int E = in_sizes[1] / 2;

    const float* eps[3] = {(const float*)d_in[2], (const float*)d_in[9], (const float*)d_in[16]};
    const float* w1[3]  = {(const float*)d_in[3], (const float*)d_in[10], (const float*)d_in[17]};
    const float* b1[3]  = {(const float*)d_in[4], (const float*)d_in[11], (const float*)d_in[18]};
    const float* w2[3]  = {(const float*)d_in[5], (const float*)d_in[12], (const float*)d_in[19]};
    const float* b2[3]  = {(const float*)d_in[6], (const float*)d_in[13], (const float*)d_in[20]};
    const float* g[3]   = {(const float*)d_in[7], (const float*)d_in[14], (const float*)d_in[21]};
    const float* bt[3]  = {(const float*)d_in[8], (const float*)d_in[15], (const float*)d_in[22]};
    const float* wl = (const float*)d_in[23];
    const float* bl = (const float*)d_in[24];

    // workspace layout (fp16 h buffers)
    __half* xh   = (__half*)d_ws;                       // N*64 fp16
    __half* ha   = xh + (size_t)N_NODES * 64;
    __half* hb   = ha + (size_t)N_NODES * 64;
    float* stats = (float*)(hb + (size_t)N_NODES * 64);
    int* gcnt    = (int*)(stats + 384);
    int* bbase   = gcnt + NB;
    int* gcursor = bbase + (NB + 1);
    int* row_ptr = gcursor + NB;
    int* tail    = row_ptr + (N_NODES + 1);
    size_t used  = (size_t)((char*)tail - (char*)d_ws);

    int* csr_src;
    int* part;
    if (used + 2 * (size_t)E * 4 <= ws_size) {
        csr_src = tail;
        part = csr_src + E;
    } else {
        part = tail;
        csr_src = (int*)d_out;  // consumed before final_k writes d_out
    }

    const int n4 = N_NODES * 16;

    // ---- partition + CSR build + x->fp16 (once) ----
    zero_misc_k<<<(NB + 255) / 256, 256, 0, stream>>>(stats, gcnt);
    tofp16_k<<<(n4 + 255) / 256, 256, 0, stream>>>(x, xh, n4);
    histA_k<<<PART_BLOCKS, 256, 0, stream>>>(ei, gcnt, E);
    scanA_k<<<1, 256, 0, stream>>>(gcnt, bbase, gcursor);
    partA_k<<<PART_BLOCKS, 256, 0, stream>>>(ei, gcursor, part, E);
    sortB_k<<<NB, 256, 0, stream>>>(part, bbase, row_ptr, csr_src);

    // ---- 3 fused GIN layers ----
    layer_k<true><<<NB, 256, 0, stream>>>(xh, nullptr, nullptr, nullptr, row_ptr, csr_src,
                                          eps[0], w1[0], b1[0], w2[0], b2[0], ha, stats + 0);
    layer_k<false><<<NB, 256, 0, stream>>>(ha, stats + 0, g[0], bt[0], row_ptr, csr_src,
                                           eps[1], w1[1], b1[1], w2[1], b2[1], hb, stats + 128);
    layer_k<false><<<NB, 256, 0, stream>>>(hb, stats + 128, g[1], bt[1], row_ptr, csr_src,
                                           eps[2], w1[2], b1[2], w2[2], b2[2], ha, stats + 256);

    // ---- final linear with BN3 fused ----
    final_k<<<NB, 256, 0, stream>>>(ha, stats + 256, g[2], bt[2], wl, bl, (float*)d_out);
}